// Round 10
// baseline (360.458 us; speedup 1.0000x reference)
//
#include <hip/hip_runtime.h>
#include <math.h>

namespace {
constexpr int NIMG = 16;
constexpr int ICH  = 3;
constexpr int OCH  = 64;
constexpr int KS   = 7;
constexpr int H    = 512;
constexpr int W    = 512;
constexpr int TX   = 64;    // out cols per block
constexpr int TY   = 4;     // out rows per block (1 per wave)
constexpr int XRR  = 11;    // staged rows: yb-3 .. yb+7
constexpr int XRP  = 80;    // xrow pitch (bf16)
constexpr int XTC  = 72;    // XT cols: p+kw = 0..70, pad 72
}

typedef float f32x4  __attribute__((ext_vector_type(4)));
typedef short bf16x8 __attribute__((ext_vector_type(8)));

__device__ __forceinline__ unsigned short f2bf(float f) {
    union { float f; unsigned u; } v; v.f = f;
    unsigned r = v.u + 0x7fff + ((v.u >> 16) & 1);   // RNE
    return (unsigned short)(r >> 16);
}

// ---- pass 1: weights -> d_ws in EXACT A-fragment order ----
// A[row=oc][k], k = kw*8 + kh (kh,kw padded to 8 with zero weights).
// frag (m-tile, k-half h): lane l holds row=16m+(l&15), k=32h+(l>>4)*8+j.
// flat idx = ((m*2+h)*64 + l)*8 + j
__global__ void make_wfrag(const float* __restrict__ scales,
                           const float* __restrict__ dirs,
                           const float* __restrict__ poss,
                           unsigned short* __restrict__ wf)
{
    for (int i = threadIdx.x; i < 4096; i += 256) {
        const int j = i & 7;
        const int l = (i >> 3) & 63;
        const int h = (i >> 9) & 1;
        const int m = i >> 10;
        const int oc = m * 16 + (l & 15);
        const int kw = 4 * h + (l >> 4);
        const int kh = j;
        float v = 0.0f;
        if (kh < KS && kw < KS) {
            const float d  = dirs[oc];
            const float tc = ((float)(kh - 3) * cosf(d) + (float)(kw - 3) * sinf(d)
                              - poss[oc]) / scales[oc];
            const float t2 = tc * tc;
            v = expf(-0.5f * t2) - 0.5f * expf(-0.125f * t2);
        }
        wf[i] = f2bf(v);
    }
}

// ---- pass 2: MFMA conv. D[oc][pixel] = A[oc][k] x B[k][pixel] ----
__global__ __launch_bounds__(256)
void ridgelet_mfma(const float* __restrict__ x,
                   const unsigned short* __restrict__ wf,
                   float* __restrict__ out)
{
    __shared__ unsigned short xrow[XRR][XRP];                 // ch-summed bf16 rows
    __shared__ __align__(16) unsigned short xt[TY][XTC][8];   // per-wave transposed slab

    const int tid  = threadIdx.x;
    const int lane = tid & 63;
    const int wv   = tid >> 6;
    const int x0   = blockIdx.x * TX;
    const int yb   = blockIdx.y * TY;
    const int n    = blockIdx.z;

    // A-frags: 4 oc-tiles x 2 k-halves, preloaded for whole kernel (32 VGPR)
    bf16x8 A[4][2];
    #pragma unroll
    for (int m = 0; m < 4; ++m)
        #pragma unroll
        for (int h = 0; h < 2; ++h)
            A[m][h] = *(const bf16x8*)(wf + (size_t)((m * 2 + h) * 64 + lane) * 8);

    // ---- stage channel-summed rows yb-3 .. yb+7, cols x0-3 .. x0+68 ----
    const float* xb = x + (size_t)n * ICH * H * W;
    for (int i = tid; i < XRR * XRP; i += 256) {
        const int r  = i / XRP;
        const int c  = i - r * XRP;
        const int gh = yb - 3 + r;
        const int gw = x0 - 3 + c;
        float s = 0.0f;
        if (c < XTC && (unsigned)gh < (unsigned)H && (unsigned)gw < (unsigned)W) {
            const size_t o = (size_t)gh * W + gw;
            s = xb[o] + xb[o + (size_t)H * W] + xb[o + 2 * (size_t)H * W];
        }
        xrow[r][c] = f2bf(s);
    }
    __syncthreads();

    // ---- build this wave's transposed slab: xt[wv][c][j] = xrow[wv+j][c] ----
    // (wave-private: written and read by the same wave; lgkmcnt orders it)
    #pragma unroll
    for (int i = 0; i < 9; ++i) {                 // 9*64 = 576 = 72*8 exactly
        const int e = i * 64 + lane;
        const int c = e >> 3;
        const int j = e & 7;
        xt[wv][c][j] = xrow[wv + j][c];
    }

    // ---- compute: 4 pixel-tiles x 4 oc-tiles x 2 k-halves = 32 mfma ----
    f32x4 acc[4][4];
    #pragma unroll
    for (int nt = 0; nt < 4; ++nt)
        #pragma unroll
        for (int mt = 0; mt < 4; ++mt)
            acc[nt][mt] = f32x4{0.f, 0.f, 0.f, 0.f};

    #pragma unroll
    for (int nt = 0; nt < 4; ++nt) {
        // B-frag: lane l -> pixel p = l&15, kw = 4h + (l>>4), col = p + kw
        const int cb = nt * 16 + (lane & 15) + (lane >> 4);
        const bf16x8 b0 = *(const bf16x8*)&xt[wv][cb][0];       // kw 0..3
        const bf16x8 b1 = *(const bf16x8*)&xt[wv][cb + 4][0];   // kw 4..7
        #pragma unroll
        for (int mt = 0; mt < 4; ++mt) {
            acc[nt][mt] = __builtin_amdgcn_mfma_f32_16x16x32_bf16(A[mt][0], b0, acc[nt][mt], 0, 0, 0);
            acc[nt][mt] = __builtin_amdgcn_mfma_f32_16x16x32_bf16(A[mt][1], b1, acc[nt][mt], 0, 0, 0);
        }
    }

    // ---- store: D col=lane&15 (pixel), row=(lane>>4)*4+reg (oc) [m89] ----
    const int y = yb + wv;
    float* ob = out + (size_t)n * OCH * H * W + (size_t)y * W + x0;
    #pragma unroll
    for (int nt = 0; nt < 4; ++nt)
        #pragma unroll
        for (int mt = 0; mt < 4; ++mt)
            #pragma unroll
            for (int r = 0; r < 4; ++r) {
                const int oc = mt * 16 + (lane >> 4) * 4 + r;
                __builtin_nontemporal_store(acc[nt][mt][r],
                    ob + (size_t)oc * (H * W) + nt * 16 + (lane & 15));
            }
}

extern "C" void kernel_launch(void* const* d_in, const int* in_sizes, int n_in,
                              void* d_out, int out_size, void* d_ws, size_t ws_size,
                              hipStream_t stream)
{
    const float* x  = (const float*)d_in[0];
    const float* sc = (const float*)d_in[1];
    const float* di = (const float*)d_in[2];
    const float* po = (const float*)d_in[3];
    float* outp     = (float*)d_out;
    unsigned short* wbuf = (unsigned short*)d_ws;   // 4096 bf16 = 8 KB

    make_wfrag<<<dim3(1), dim3(256), 0, stream>>>(sc, di, po, wbuf);

    dim3 grid(W / TX, H / TY, NIMG);   // 8 x 128 x 16 = 16384 blocks
    ridgelet_mfma<<<grid, dim3(256), 0, stream>>>(x, wbuf, outp);
}

// Round 11
// 217.844 us; speedup vs baseline: 1.6547x; 1.6547x over previous
//
#include <hip/hip_runtime.h>
#include <math.h>

namespace {
constexpr int NIMG = 16;
constexpr int ICH  = 3;
constexpr int OCH  = 64;
constexpr int KS   = 7;
constexpr int H    = 512;
constexpr int W    = 512;
constexpr int TX   = 64;    // out cols per block
constexpr int TY   = 4;     // out rows per block (1 per wave)
constexpr int XRR  = 11;    // staged rows: yb-3 .. yb+7
constexpr int XRP  = 80;    // xrow pitch (bf16)
constexpr int XTC  = 72;    // XT cols: p+kw = 0..70, pad 72
constexpr int OSP  = 68;    // ostage pitch (floats): 4-row group offset 16 banks
}

typedef float f32x4  __attribute__((ext_vector_type(4)));
typedef short bf16x8 __attribute__((ext_vector_type(8)));

__device__ __forceinline__ unsigned short f2bf(float f) {
    union { float f; unsigned u; } v; v.f = f;
    unsigned r = v.u + 0x7fff + ((v.u >> 16) & 1);   // RNE
    return (unsigned short)(r >> 16);
}

// ---- pass 1: weights -> d_ws in EXACT A-fragment order ----
// A[row=oc][k], k = kw*8 + kh (kh,kw padded to 8 with zero weights).
// frag (m-tile, k-half h): lane l holds row=16m+(l&15), k=32h+(l>>4)*8+j.
__global__ void make_wfrag(const float* __restrict__ scales,
                           const float* __restrict__ dirs,
                           const float* __restrict__ poss,
                           unsigned short* __restrict__ wf)
{
    for (int i = threadIdx.x; i < 4096; i += 256) {
        const int j = i & 7;
        const int l = (i >> 3) & 63;
        const int h = (i >> 9) & 1;
        const int m = i >> 10;
        const int oc = m * 16 + (l & 15);
        const int kw = 4 * h + (l >> 4);
        const int kh = j;
        float v = 0.0f;
        if (kh < KS && kw < KS) {
            const float d  = dirs[oc];
            const float tc = ((float)(kh - 3) * cosf(d) + (float)(kw - 3) * sinf(d)
                              - poss[oc]) / scales[oc];
            const float t2 = tc * tc;
            v = expf(-0.5f * t2) - 0.5f * expf(-0.125f * t2);
        }
        wf[i] = f2bf(v);
    }
}

// ---- pass 2: MFMA conv. D[oc][pixel] = A[oc][k] x B[k][pixel] ----
__global__ __launch_bounds__(256)
void ridgelet_mfma(const float* __restrict__ x,
                   const unsigned short* __restrict__ wf,
                   float* __restrict__ out)
{
    __shared__ unsigned short xrow[XRR][XRP];                 // ch-summed bf16 rows
    __shared__ __align__(16) unsigned short xt[TY][XTC][8];   // per-wave transposed slab
    __shared__ __align__(16) float ostage[TY][32][OSP];       // per-wave store bounce

    const int tid  = threadIdx.x;
    const int lane = tid & 63;
    const int wv   = tid >> 6;
    const int x0   = blockIdx.x * TX;
    const int yb   = blockIdx.y * TY;
    const int n    = blockIdx.z;

    // A-frags: 4 oc-tiles x 2 k-halves, preloaded for whole kernel (32 VGPR)
    bf16x8 A[4][2];
    #pragma unroll
    for (int m = 0; m < 4; ++m)
        #pragma unroll
        for (int h = 0; h < 2; ++h)
            A[m][h] = *(const bf16x8*)(wf + (size_t)((m * 2 + h) * 64 + lane) * 8);

    // ---- stage channel-summed rows yb-3 .. yb+7, cols x0-3 .. x0+68 ----
    const float* xb = x + (size_t)n * ICH * H * W;
    for (int i = tid; i < XRR * XRP; i += 256) {
        const int r  = i / XRP;
        const int c  = i - r * XRP;
        const int gh = yb - 3 + r;
        const int gw = x0 - 3 + c;
        float s = 0.0f;
        if (c < XTC && (unsigned)gh < (unsigned)H && (unsigned)gw < (unsigned)W) {
            const size_t o = (size_t)gh * W + gw;
            s = xb[o] + xb[o + (size_t)H * W] + xb[o + 2 * (size_t)H * W];
        }
        xrow[r][c] = f2bf(s);
    }
    __syncthreads();

    // ---- build this wave's transposed slab: xt[wv][c][j] = xrow[wv+j][c] ----
    #pragma unroll
    for (int i = 0; i < 9; ++i) {                 // 9*64 = 576 = 72*8 exactly
        const int e = i * 64 + lane;
        const int c = e >> 3;
        const int j = e & 7;
        xt[wv][c][j] = xrow[wv + j][c];
    }

    // ---- compute: 4 pixel-tiles x 4 oc-tiles x 2 k-halves = 32 mfma ----
    f32x4 acc[4][4];
    #pragma unroll
    for (int nt = 0; nt < 4; ++nt)
        #pragma unroll
        for (int mt = 0; mt < 4; ++mt)
            acc[nt][mt] = f32x4{0.f, 0.f, 0.f, 0.f};

    #pragma unroll
    for (int nt = 0; nt < 4; ++nt) {
        // B-frag: lane l -> pixel p = l&15, kw = 4h + (l>>4), col = p + kw
        const int cb = nt * 16 + (lane & 15) + (lane >> 4);
        const bf16x8 b0 = *(const bf16x8*)&xt[wv][cb][0];       // kw 0..3
        const bf16x8 b1 = *(const bf16x8*)&xt[wv][cb + 4][0];   // kw 4..7
        #pragma unroll
        for (int mt = 0; mt < 4; ++mt) {
            acc[nt][mt] = __builtin_amdgcn_mfma_f32_16x16x32_bf16(A[mt][0], b0, acc[nt][mt], 0, 0, 0);
            acc[nt][mt] = __builtin_amdgcn_mfma_f32_16x16x32_bf16(A[mt][1], b1, acc[nt][mt], 0, 0, 0);
        }
    }

    // ---- epilogue: LDS bounce -> full-line dwordx4 stores ----
    // D layout [m89]: col=lane&15 (pixel), row=(lane>>4)*4+reg (oc-within-16).
    // Two rounds of 32 oc each; ostage is wave-private (lgkmcnt orders it).
    const int y = yb + wv;
    float* ob = out + (size_t)n * OCH * H * W + (size_t)y * W + x0;

    #pragma unroll
    for (int rd = 0; rd < 2; ++rd) {
        #pragma unroll
        for (int mh = 0; mh < 2; ++mh) {
            const int mt = rd * 2 + mh;
            #pragma unroll
            for (int nt = 0; nt < 4; ++nt)
                #pragma unroll
                for (int r = 0; r < 4; ++r) {
                    const int ocl = mh * 16 + (lane >> 4) * 4 + r;
                    const int px  = nt * 16 + (lane & 15);
                    ostage[wv][ocl][px] = acc[nt][mt][r];
                }
        }
        // read back: lane -> 4 consecutive px of one oc; 16 lanes = 256B/row
        #pragma unroll
        for (int i = 0; i < 8; ++i) {
            const int ocl = i * 4 + (lane >> 4);
            const int px4 = (lane & 15) * 4;
            const f32x4 vs = *(const f32x4*)&ostage[wv][ocl][px4];
            const int oc = rd * 32 + ocl;
            __builtin_nontemporal_store(vs, (f32x4*)(ob + (size_t)oc * (H * W) + px4));
        }
    }
}

extern "C" void kernel_launch(void* const* d_in, const int* in_sizes, int n_in,
                              void* d_out, int out_size, void* d_ws, size_t ws_size,
                              hipStream_t stream)
{
    const float* x  = (const float*)d_in[0];
    const float* sc = (const float*)d_in[1];
    const float* di = (const float*)d_in[2];
    const float* po = (const float*)d_in[3];
    float* outp     = (float*)d_out;
    unsigned short* wbuf = (unsigned short*)d_ws;   // 4096 bf16 = 8 KB

    make_wfrag<<<dim3(1), dim3(256), 0, stream>>>(sc, di, po, wbuf);

    dim3 grid(W / TX, H / TY, NIMG);   // 8 x 128 x 16 = 16384 blocks
    ridgelet_mfma<<<grid, dim3(256), 0, stream>>>(x, wbuf, outp);
}